// Round 13
// baseline (212.821 us; speedup 1.0000x reference)
//
#include <hip/hip_runtime.h>

#define DEV __device__ __forceinline__

typedef unsigned short u16;
typedef __attribute__((ext_vector_type(8))) short bf16x8;   // 8 bf16 (4 VGPRs)
typedef __attribute__((ext_vector_type(8))) unsigned short u16x8;
typedef __attribute__((ext_vector_type(4))) float f32x4;

constexpr int Bz = 32, Lz = 1024, Dz = 384, Fz = 384, KWz = 3, Mz = 4096;
constexpr float EPS = 1e-5f;

DEV u16 f2bf(float f) {  // RNE f32 -> bf16
  unsigned u = __float_as_uint(f);
  u += 0x7fffu + ((u >> 16) & 1u);
  return (u16)(u >> 16);
}

typedef __attribute__((address_space(1))) const unsigned char ga_t;
typedef __attribute__((address_space(3))) unsigned char la_t;
DEV void gload16(const void* g, void* l) {
  // async global->LDS, 16B per lane; LDS dest is wave-uniform base + lane*16
  __builtin_amdgcn_global_load_lds((ga_t*)g, (la_t*)l, 16, 0, 0);
}

#define WAITV(n) asm volatile("s_waitcnt vmcnt(" #n ")" ::: "memory")

// ---------- prep: weight transpose+cvt, h1 halo zero, cumsum+search ---------
__global__ __launch_bounds__(1024) void k_pre(
    const float* __restrict__ w1, const float* __restrict__ w2,
    u16* __restrict__ w1t, u16* __restrict__ w2t, u16* __restrict__ h1,
    const int* __restrict__ tgt, int* __restrict__ idxb) {
  __shared__ int sc[Lz];
  constexpr int WT = KWz * Fz * Dz;                     // 442368
  constexpr int PREP_ELEMS = 2 * WT + Bz * 2 * Dz;      // 909312
  constexpr int PREP_BLKS = (PREP_ELEMS + 1023) / 1024; // 888
  const int tid = threadIdx.x;

  if (blockIdx.x < PREP_BLKS) {
    int gid = blockIdx.x * 1024 + tid;
    if (gid < WT) {
      int k = gid / (Fz * Dz), rem = gid % (Fz * Dz);
      int f = rem / Dz, d = rem % Dz;
      w1t[gid] = f2bf(w1[(f * Dz + d) * KWz + k]);
    } else if (gid < 2 * WT) {
      int g2 = gid - WT;
      int k = g2 / (Fz * Fz), rem = g2 % (Fz * Fz);
      int co = rem / Fz, ci = rem % Fz;
      w2t[g2] = f2bf(w2[(co * Fz + ci) * KWz + k]);
    } else if (gid < PREP_ELEMS) {
      int p = gid - 2 * WT;  // h1 halo rows
      int b = p / (2 * Dz), r = (p / Dz) & 1, d = p % Dz;
      size_t row = (size_t)b * (Lz + 2) + (r ? (Lz + 1) : 0);
      h1[row * Dz + d] = 0;
    }
    return;
  }
  // ---- cumsum + searchsorted(right) ----
  int b = blockIdx.x - PREP_BLKS;
  sc[tid] = tgt[b * Lz + tid];
  __syncthreads();
  for (int off = 1; off < Lz; off <<= 1) {
    int add = (tid >= off) ? sc[tid - off] : 0;
    __syncthreads();
    sc[tid] += add;
    __syncthreads();
  }
  int total = sc[Lz - 1];
  for (int t = tid; t < Mz; t += 1024) {
    int lo = 0, hi = Lz;
    while (lo < hi) {
      int mid = (lo + hi) >> 1;
      if (sc[mid] > t) hi = mid; else lo = mid + 1;
    }
    int iv = (t < total) ? (lo > Lz - 1 ? Lz - 1 : lo) : -1;
    idxb[b * Mz + t] = iv;
  }
}

// --------- fused conv1d(K=3,'same') + LayerNorm + ReLU (+ final dot) --------
// Waves 0-7: R12 conv schedule VERBATIM (taps-inner, granule-major A, 3-buf B,
//   counted vmcnt, setprio around MFMA). Waves 8-11: latency-decoupled gather
//   (idx prefetched to lane regs, depth-3 pair pipeline, literal slots),
//   matching the conv barrier cadence exactly: 36 + 2 + (LAYER==2) barriers.
// __launch_bounds__(768,2) -> VGPR cap 256 (R5/R6's (768,3)=170 cap is the
// suspected spill cause of the earlier fusion failures).
template <int LAYER>
__global__ __launch_bounds__(768, 2) void k_conv(
    const void* __restrict__ Asrc, // LAYER1: x f32 [B][1024][384]; L2: h1 bf16
    const u16* __restrict__ wt,    // [3][384 out][384 in] bf16
    const float* __restrict__ cbias,
    const float* __restrict__ lng, const float* __restrict__ lnb,
    u16* __restrict__ hout,        // LAYER==1: padded output buffer
    const float* __restrict__ lw, const float* __restrict__ lbias,
    float* __restrict__ dur,       // LAYER==2: [B*L]
    const float* __restrict__ xf,  // gather: source rows (f32)
    const int* __restrict__ idxb,  // gather: per-frame idx (-1 = pad)
    float* __restrict__ out0)      // gather: [B*M*D]
{
  constexpr int ABUFS = (LAYER == 1) ? 2 : 3;
  __shared__ __align__(16) u16 Ash[ABUFS][8192];   // 16KB per buf
  __shared__ __align__(16) u16 Bsh[3][384 * 32];   // 3 x 24KB
  __shared__ float s_sum[4][128], s_sq[4][128], s_dot[4][128];

  const int tid = threadIdx.x;
  const int lane = tid & 63, wave = tid >> 6;   // 12 waves: 8 conv + 4 gather
  const int l15 = lane & 15, lh = lane >> 4;
  const int b = blockIdx.x >> 3, l0 = (blockIdx.x & 7) << 7;
  const bf16x8 zfrag = {0, 0, 0, 0, 0, 0, 0, 0};

  if (wave >= 8) {  // ================= gather waves =================
    const int gw = wave - 8;
    const int rbase = (LAYER == 1 ? 0 : (Bz * Mz) / 2) + blockIdx.x * 256 + gw * 64;
    const int myidx = idxb[rbase + lane];   // one coalesced idx load pre-loop

    float4 A0[3], B0[3], A1[3], B1[3];      // 3 slots, literal-indexed only

    auto ldpair = [&](int p, float4& a0, float4& b0q, float4& a1, float4& b1q) {
      int r0 = rbase + 2 * p;
      int iv0 = __shfl(myidx, 2 * p), iv1 = __shfl(myidx, 2 * p + 1);
      if (iv0 < 0) { a0 = make_float4(0.f, 0.f, 0.f, 0.f); b0q = a0; }
      else {
        const float4* s =
            reinterpret_cast<const float4*>(xf + ((size_t)(r0 >> 12) * Lz + iv0) * Dz);
        a0 = s[lane]; b0q = (lane < 32) ? s[64 + lane] : a0;
      }
      if (iv1 < 0) { a1 = make_float4(0.f, 0.f, 0.f, 0.f); b1q = a1; }
      else {
        const float4* s =
            reinterpret_cast<const float4*>(xf + ((size_t)((r0 + 1) >> 12) * Lz + iv1) * Dz);
        a1 = s[lane]; b1q = (lane < 32) ? s[64 + lane] : a1;
      }
    };
    auto stpair = [&](int p, float4 a0, float4 b0q, float4 a1, float4 b1q) {
      int r0 = rbase + 2 * p;
      float4* d0 = reinterpret_cast<float4*>(out0 + (size_t)r0 * Dz);
      d0[lane] = a0; if (lane < 32) d0[64 + lane] = b0q;
      float4* d1 = reinterpret_cast<float4*>(out0 + (size_t)(r0 + 1) * Dz);
      d1[lane] = a1; if (lane < 32) d1[64 + lane] = b1q;
    };

    ldpair(0, A0[0], B0[0], A1[0], B1[0]);
    ldpair(1, A0[1], B0[1], A1[1], B1[1]);
    // interval kt: load pair kt+2 -> slot (kt+2)%3; store pair kt from kt%3
    for (int k3 = 0; k3 < 12; ++k3) {
      int kt = 3 * k3;
      if (kt < 30) ldpair(kt + 2, A0[2], B0[2], A1[2], B1[2]);
      if (kt < 32) stpair(kt, A0[0], B0[0], A1[0], B1[0]);
      __builtin_amdgcn_s_barrier();            // kt = 3k3
      ++kt;
      if (kt < 30) ldpair(kt + 2, A0[0], B0[0], A1[0], B1[0]);
      if (kt < 32) stpair(kt, A0[1], B0[1], A1[1], B1[1]);
      __builtin_amdgcn_s_barrier();            // kt = 3k3+1
      ++kt;
      if (kt < 30) ldpair(kt + 2, A0[1], B0[1], A1[1], B1[1]);
      if (kt < 32) stpair(kt, A0[2], B0[2], A1[2], B1[2]);
      __builtin_amdgcn_s_barrier();            // kt = 3k3+2
    }
    __builtin_amdgcn_s_barrier();                // 37
    __builtin_amdgcn_s_barrier();                // 38
    if constexpr (LAYER == 2) __builtin_amdgcn_s_barrier();  // 39
    return;
  }

  // ================= conv waves (R12 code verbatim) =================
  const int wr = wave >> 2, wc = wave & 3;      // 2 x 4 wave grid

  int bgof[3], bldo[3];
  #pragma unroll
  for (int i = 0; i < 3; ++i) {
    int c = wave + 8 * i;
    int slot = c * 64 + lane, f = slot >> 2, q = slot & 3;
    int ks = q ^ ((f >> 1) & 3);             // XOR slot swizzle (involution)
    bgof[i] = f * 384 + ks * 8;
    bldo[i] = c * 512;
  }
  auto STAGE_B = [&](int kt) {               // B(kt) -> Bsh[kt%3]
    int tap = kt % 3, dw = kt / 3;
    const u16* sb = wt + tap * (384 * 384) + dw * 32;
    u16* dst = Bsh[tap];
    #pragma unroll
    for (int i = 0; i < 3; ++i) gload16(sb + bgof[i], dst + bldo[i]);
  };

  const float* arow_ptr = nullptr;           // LAYER1
  const u16* a2src[2] = {nullptr, nullptr};  // LAYER2
  int a2ldo[2] = {0, 0};
  float4 ar0, ar1, ar2, ar3;
  if constexpr (LAYER == 1) {
    int r1 = tid & 255, g1 = tid >> 8;       // tid < 512 here
    int grow = l0 - 1 + r1;
    if (grow > l0 + 135) grow = l0 + 135;    // rows >135 never read: dedupe
    if (grow < 0) grow = 0;
    if (grow > Lz - 1) grow = Lz - 1;
    arow_ptr = (const float*)Asrc + (size_t)b * Lz * 384 + (size_t)grow * 384 +
               g1 * 8;
  } else {
    #pragma unroll
    for (int i = 0; i < 2; ++i) {
      int c = wave + 8 * i;                  // 16 chunks of 1KB
      int s = c * 64 + lane, g = s >> 8, r = s & 255;
      int p = l0 + r;                        // padded row index
      if (p > l0 + 135) p = l0 + 135;
      if (p > Lz + 1) p = Lz + 1;
      a2src[i] = (const u16*)Asrc + (size_t)b * (Lz + 2) * 384 +
                 (size_t)p * 384 + g * 8;
      a2ldo[i] = c * 512;
    }
  }
  auto AISSUE = [&](int w) {                 // LAYER1: load window-w regs
    const float* p = arow_ptr + w * 32;
    ar0 = *reinterpret_cast<const float4*>(p);
    ar1 = *reinterpret_cast<const float4*>(p + 4);
    ar2 = *reinterpret_cast<const float4*>(p + 16);
    ar3 = *reinterpret_cast<const float4*>(p + 20);
  };
  auto ADSW = [&](int wbuf) {                // LAYER1: regs -> LDS bf16
    u16x8 h0, h1;
    h0[0] = f2bf(ar0.x); h0[1] = f2bf(ar0.y); h0[2] = f2bf(ar0.z); h0[3] = f2bf(ar0.w);
    h0[4] = f2bf(ar1.x); h0[5] = f2bf(ar1.y); h0[6] = f2bf(ar1.z); h0[7] = f2bf(ar1.w);
    h1[0] = f2bf(ar2.x); h1[1] = f2bf(ar2.y); h1[2] = f2bf(ar2.z); h1[3] = f2bf(ar2.w);
    h1[4] = f2bf(ar3.x); h1[5] = f2bf(ar3.y); h1[6] = f2bf(ar3.z); h1[7] = f2bf(ar3.w);
    *reinterpret_cast<u16x8*>(&Ash[wbuf][tid * 8]) = h0;
    *reinterpret_cast<u16x8*>(&Ash[wbuf][(tid + 512) * 8]) = h1;
  };
  auto STAGE_A2 = [&](int w, int buf) {      // LAYER2: async A window stage
    #pragma unroll
    for (int i = 0; i < 2; ++i) gload16(a2src[i] + w * 32, &Ash[buf][a2ldo[i]]);
  };

  int tr[4], boff[6];
  #pragma unroll
  for (int m = 0; m < 4; ++m) tr[m] = wr * 64 + m * 16 + l15;
  #pragma unroll
  for (int n = 0; n < 6; ++n) {
    int c = wc * 96 + n * 16 + l15;
    boff[n] = c * 32 + (lh ^ ((c >> 1) & 3)) * 8;
  }

  f32x4 acc[4][6] = {};

  // ---- prologue ----
  if constexpr (LAYER == 1) {
    AISSUE(0);
    WAITV(0);
    ADSW(0);
    AISSUE(1);
    __builtin_amdgcn_sched_barrier(0);  // pin: aregs(1) issued before B(0),B(1)
    STAGE_B(0);
    STAGE_B(1);
  } else {
    STAGE_A2(0, 0);
    STAGE_B(0);
    STAGE_A2(1, 1);
    STAGE_B(1);
  }

#define PHASE(T)                                                               \
  {                                                                            \
    if constexpr ((T) == 0) {                                                  \
      if constexpr (LAYER == 2) {                                              \
        if (w == 0) { WAITV(5); } else { WAITV(3); }                           \
      } else { WAITV(3); }                                                     \
    } else if constexpr ((T) == 1) {                                           \
      if (w <= 9) {                                                            \
        if constexpr (LAYER == 1) { WAITV(7); } else { WAITV(5); }             \
      } else { WAITV(3); }                                                     \
    } else {                                                                   \
      if (w <= 9) {                                                            \
        if constexpr (LAYER == 1) { WAITV(7); } else { WAITV(5); }             \
      } else if (w == 10) { WAITV(3); } else { WAITV(0); }                     \
    }                                                                          \
    asm volatile("s_waitcnt lgkmcnt(0)" ::: "memory");                         \
    __builtin_amdgcn_s_barrier();                                              \
    __builtin_amdgcn_sched_barrier(0);                                         \
    const int abuf_ = (LAYER == 1) ? (w & 1) : (w % 3);                        \
    bf16x8 av[4], bv[6];                                                       \
    _Pragma("unroll")                                                          \
    for (int m = 0; m < 4; ++m) {                                              \
      av[m] = *reinterpret_cast<const bf16x8*>(                                \
          &Ash[abuf_][(lh * 256 + tr[m] + (T)) * 8]);                          \
      if constexpr (LAYER == 1 && (T) != 1) {                                  \
        int gr = l0 + tr[m] + (T) - 1;                                         \
        if ((unsigned)gr > (unsigned)(Lz - 1)) av[m] = zfrag;                  \
      }                                                                        \
    }                                                                          \
    _Pragma("unroll")                                                          \
    for (int n = 0; n < 6; ++n)                                                \
      bv[n] = *reinterpret_cast<const bf16x8*>(&Bsh[(T)][boff[n]]);            \
    __builtin_amdgcn_sched_barrier(0);                                         \
    { int kt2_ = 3 * w + (T) + 2; if (kt2_ <= 35) STAGE_B(kt2_); }             \
    __builtin_amdgcn_sched_barrier(0);                                         \
    if constexpr (LAYER == 1 && (T) == 0) {                                    \
      if (w <= 10) ADSW((w + 1) & 1);  /* after av reads, before AISSUE */     \
    }                                                                          \
    if constexpr ((T) == 0) {                                                  \
      if (w <= 9) {                                                            \
        if constexpr (LAYER == 1) { AISSUE(w + 2); }                           \
        else { STAGE_A2(w + 2, (w + 2) % 3); }                                 \
      }                                                                        \
    }                                                                          \
    __builtin_amdgcn_sched_barrier(0);                                         \
    __builtin_amdgcn_s_setprio(1);                                             \
    _Pragma("unroll")                                                          \
    for (int m = 0; m < 4; ++m)                                                \
      _Pragma("unroll")                                                        \
      for (int n = 0; n < 6; ++n)                                              \
        acc[m][n] = __builtin_amdgcn_mfma_f32_16x16x32_bf16(av[m], bv[n],      \
                                                            acc[m][n], 0, 0, 0);\
    __builtin_amdgcn_s_setprio(0);                                             \
  }

  for (int w = 0; w < 12; ++w) {
    PHASE(0)
    PHASE(1)
    PHASE(2)
  }
#undef PHASE

  // ---- epilogue: bias + LayerNorm(F) + ReLU, then store bf16 or dot(lw) ----
  __syncthreads();                             // 37
  float gv[6], bvv[6], cbv[6], lwv[6];
  #pragma unroll
  for (int n = 0; n < 6; ++n) {
    int c = wc * 96 + n * 16 + l15;
    gv[n] = lng[c]; bvv[n] = lnb[c]; cbv[n] = cbias[c];
    lwv[n] = (LAYER == 2) ? lw[c] : 0.f;
  }
  #pragma unroll
  for (int m = 0; m < 4; ++m) {
    #pragma unroll
    for (int r = 0; r < 4; ++r) {
      float s = 0.f, q2 = 0.f;
      #pragma unroll
      for (int n = 0; n < 6; ++n) {
        float v = acc[m][n][r] + cbv[n];
        s += v; q2 += v * v;
      }
      #pragma unroll
      for (int off = 1; off < 16; off <<= 1) {
        s += __shfl_xor(s, off);
        q2 += __shfl_xor(q2, off);
      }
      if (l15 == 0) {
        int row = wr * 64 + m * 16 + lh * 4 + r;
        s_sum[wc][row] = s;
        s_sq[wc][row] = q2;
      }
    }
  }
  __syncthreads();                             // 38
  #pragma unroll
  for (int m = 0; m < 4; ++m) {
    #pragma unroll
    for (int r = 0; r < 4; ++r) {
      int row = wr * 64 + m * 16 + lh * 4 + r;
      float S = 0.f, Q = 0.f;
      #pragma unroll
      for (int w = 0; w < 4; ++w) { S += s_sum[w][row]; Q += s_sq[w][row]; }
      float mean = S * (1.f / 384.f);
      float var = Q * (1.f / 384.f) - mean * mean;
      float rstd = rsqrtf(var + EPS);
      float dotp = 0.f;
      #pragma unroll
      for (int n = 0; n < 6; ++n) {
        float v = acc[m][n][r] + cbv[n];
        float y = fmaxf((v - mean) * rstd * gv[n] + bvv[n], 0.f);
        if constexpr (LAYER == 1) {
          int c = wc * 96 + n * 16 + l15;
          hout[((size_t)(b * (Lz + 2) + l0 + row + 1)) * 384 + c] = f2bf(y);
        } else {
          dotp += y * lwv[n];
        }
      }
      if constexpr (LAYER == 2) {
        #pragma unroll
        for (int off = 1; off < 16; off <<= 1) dotp += __shfl_xor(dotp, off);
        if (l15 == 0) s_dot[wc][row] = dotp;
      }
    }
  }
  if constexpr (LAYER == 2) {
    __syncthreads();                           // 39
    if (tid < 128) {
      float dsum = lbias[0];
      #pragma unroll
      for (int w = 0; w < 4; ++w) dsum += s_dot[w][tid];
      dur[(size_t)b * Lz + l0 + tid] = fmaxf(dsum, 0.f);
    }
  }
}

extern "C" void kernel_launch(void* const* d_in, const int* in_sizes, int n_in,
                              void* d_out, int out_size, void* d_ws, size_t ws_size,
                              hipStream_t stream) {
  (void)in_sizes; (void)n_in; (void)out_size; (void)ws_size;
  const float* x   = (const float*)d_in[0];
  const int* tgt   = (const int*)d_in[1];
  const float* w1  = (const float*)d_in[3];
  const float* c1b = (const float*)d_in[4];
  const float* g1  = (const float*)d_in[5];
  const float* b1  = (const float*)d_in[6];
  const float* w2  = (const float*)d_in[7];
  const float* c2b = (const float*)d_in[8];
  const float* g2  = (const float*)d_in[9];
  const float* b2  = (const float*)d_in[10];
  const float* lw  = (const float*)d_in[11];
  const float* lb  = (const float*)d_in[12];

  float* out0 = (float*)d_out;
  float* dur  = out0 + (size_t)Bz * Mz * Dz;

  const size_t h1_n = (size_t)Bz * (Lz + 2) * Dz;  // 12,607,488 bf16
  const size_t wt_n = (size_t)KWz * Fz * Dz;       // 442,368 bf16
  u16* h1  = (u16*)d_ws;
  u16* w1t = h1 + h1_n;
  u16* w2t = w1t + wt_n;
  int* idxb = (int*)(w2t + wt_n);  // byte offset divisible by 4

  constexpr int PREP_BLKS =
      (2 * KWz * Fz * Dz + Bz * 2 * Dz + 1023) / 1024;  // 888
  k_pre<<<PREP_BLKS + Bz, 1024, 0, stream>>>(w1, w2, w1t, w2t, h1, tgt, idxb);
  k_conv<1><<<256, 768, 0, stream>>>(x, w1t, c1b, g1, b1, h1, nullptr, nullptr,
                                     nullptr, x, idxb, out0);
  k_conv<2><<<256, 768, 0, stream>>>(h1, w2t, c2b, g2, b2, nullptr, lw, lb, dur,
                                     x, idxb, out0);
}

// Round 15
// 119.253 us; speedup vs baseline: 1.7846x; 1.7846x over previous
//
#include <hip/hip_runtime.h>

#define DEV __device__ __forceinline__

typedef unsigned short u16;
typedef __attribute__((ext_vector_type(8))) short bf16x8;   // 8 bf16 (4 VGPRs)
typedef __attribute__((ext_vector_type(8))) unsigned short u16x8;
typedef __attribute__((ext_vector_type(4))) float f32x4;

constexpr int Bz = 32, Lz = 1024, Dz = 384, Fz = 384, KWz = 3, Mz = 4096;
constexpr float EPS = 1e-5f;

DEV u16 f2bf(float f) {  // RNE f32 -> bf16
  unsigned u = __float_as_uint(f);
  u += 0x7fffu + ((u >> 16) & 1u);
  return (u16)(u >> 16);
}

typedef __attribute__((address_space(1))) const unsigned char ga_t;
typedef __attribute__((address_space(3))) unsigned char la_t;
DEV void gload16(const void* g, void* l) {
  // async global->LDS, 16B per lane; LDS dest is wave-uniform base + lane*16
  __builtin_amdgcn_global_load_lds((ga_t*)g, (la_t*)l, 16, 0, 0);
}

#define WAITV(n) asm volatile("s_waitcnt vmcnt(" #n ")" ::: "memory")

// ---------- prep: weight transpose+cvt, h1 halo zero, cumsum+search ---------
__global__ __launch_bounds__(1024) void k_pre(
    const float* __restrict__ w1, const float* __restrict__ w2,
    u16* __restrict__ w1t, u16* __restrict__ w2t, u16* __restrict__ h1,
    const int* __restrict__ tgt, int* __restrict__ idxb) {
  __shared__ int sc[Lz];
  constexpr int WT = KWz * Fz * Dz;                     // 442368
  constexpr int PREP_ELEMS = 2 * WT + Bz * 2 * Dz;      // 909312
  constexpr int PREP_BLKS = (PREP_ELEMS + 1023) / 1024; // 888
  const int tid = threadIdx.x;

  if (blockIdx.x < PREP_BLKS) {
    int gid = blockIdx.x * 1024 + tid;
    if (gid < WT) {
      int k = gid / (Fz * Dz), rem = gid % (Fz * Dz);
      int f = rem / Dz, d = rem % Dz;
      w1t[gid] = f2bf(w1[(f * Dz + d) * KWz + k]);
    } else if (gid < 2 * WT) {
      int g2 = gid - WT;
      int k = g2 / (Fz * Fz), rem = g2 % (Fz * Fz);
      int co = rem / Fz, ci = rem % Fz;
      w2t[g2] = f2bf(w2[(co * Fz + ci) * KWz + k]);
    } else if (gid < PREP_ELEMS) {
      int p = gid - 2 * WT;  // h1 halo rows
      int b = p / (2 * Dz), r = (p / Dz) & 1, d = p % Dz;
      size_t row = (size_t)b * (Lz + 2) + (r ? (Lz + 1) : 0);
      h1[row * Dz + d] = 0;
    }
    return;
  }
  // ---- cumsum + searchsorted(right) ----
  int b = blockIdx.x - PREP_BLKS;
  sc[tid] = tgt[b * Lz + tid];
  __syncthreads();
  for (int off = 1; off < Lz; off <<= 1) {
    int add = (tid >= off) ? sc[tid - off] : 0;
    __syncthreads();
    sc[tid] += add;
    __syncthreads();
  }
  int total = sc[Lz - 1];
  for (int t = tid; t < Mz; t += 1024) {
    int lo = 0, hi = Lz;
    while (lo < hi) {
      int mid = (lo + hi) >> 1;
      if (sc[mid] > t) hi = mid; else lo = mid + 1;
    }
    int iv = (t < total) ? (lo > Lz - 1 ? Lz - 1 : lo) : -1;
    idxb[b * Mz + t] = iv;
  }
}

// ------------------------------ gather rows ---------------------------------
// nt stores: the 201MB output stream is write-once — keep it out of L2 so the
// re-read x rows (durations avg ~2 -> ~50% read reuse) stay resident.
__global__ void k_gather(const float* __restrict__ x, const int* __restrict__ idxb,
                         float* __restrict__ out) {
  int wid = (blockIdx.x * blockDim.x + threadIdx.x) >> 6;
  int lane = threadIdx.x & 63;
  int nw = (gridDim.x * blockDim.x) >> 6;
  for (int row = wid; row < Bz * Mz; row += nw) {
    int b = row >> 12;  // Mz = 4096
    int iv = idxb[row];
    f32x4* dst = reinterpret_cast<f32x4*>(out + (size_t)row * Dz);
    if (iv < 0) {
      f32x4 z = {0.f, 0.f, 0.f, 0.f};
      __builtin_nontemporal_store(z, dst + lane);
      if (lane < 32) __builtin_nontemporal_store(z, dst + 64 + lane);
    } else {
      const f32x4* src =
          reinterpret_cast<const f32x4*>(x + ((size_t)b * Lz + iv) * Dz);
      f32x4 a = src[lane];
      __builtin_nontemporal_store(a, dst + lane);
      if (lane < 32) {
        f32x4 c = src[64 + lane];
        __builtin_nontemporal_store(c, dst + 64 + lane);
      }
    }
  }
}

// --------- fused conv1d(K=3,'same') + LayerNorm + ReLU (+ final dot) --------
// R12 winner verbatim: taps-inner (kt = 3w + t), granule-major A in LDS,
// 3-buf B via global_load_lds, counted vmcnt + raw s_barrier, setprio around
// the MFMA cluster, ADSW after av reads. ~830 TF/conv = the plain-HIP
// 128-tile structural ceiling (m97).
template <int LAYER>
__global__ __launch_bounds__(512, 2) void k_conv(
    const void* __restrict__ Asrc, // LAYER1: x f32 [B][1024][384]; L2: h1 bf16
    const u16* __restrict__ wt,    // [3][384 out][384 in] bf16
    const float* __restrict__ cbias,
    const float* __restrict__ lng, const float* __restrict__ lnb,
    u16* __restrict__ hout,        // LAYER==1: padded output buffer
    const float* __restrict__ lw, const float* __restrict__ lbias,
    float* __restrict__ dur)       // LAYER==2: [B*L]
{
  constexpr int ABUFS = (LAYER == 1) ? 2 : 3;
  __shared__ __align__(16) u16 Ash[ABUFS][8192];   // 16KB per buf
  __shared__ __align__(16) u16 Bsh[3][384 * 32];   // 3 x 24KB
  __shared__ float s_sum[4][128], s_sq[4][128], s_dot[4][128];

  const int tid = threadIdx.x;
  const int lane = tid & 63, wave = tid >> 6;   // 8 waves
  const int wr = wave >> 2, wc = wave & 3;      // 2 x 4 wave grid
  const int l15 = lane & 15, lh = lane >> 4;
  const int b = blockIdx.x >> 3, l0 = (blockIdx.x & 7) << 7;
  const bf16x8 zfrag = {0, 0, 0, 0, 0, 0, 0, 0};

  // ---- B staging: 24 chunks of 1KB, wave w takes chunks w, w+8, w+16 ------
  int bgof[3], bldo[3];
  #pragma unroll
  for (int i = 0; i < 3; ++i) {
    int c = wave + 8 * i;
    int slot = c * 64 + lane, f = slot >> 2, q = slot & 3;
    int ks = q ^ ((f >> 1) & 3);             // XOR slot swizzle (involution)
    bgof[i] = f * 384 + ks * 8;
    bldo[i] = c * 512;
  }
  auto STAGE_B = [&](int kt) {               // B(kt) -> Bsh[kt%3]
    int tap = kt % 3, dw = kt / 3;
    const u16* sb = wt + tap * (384 * 384) + dw * 32;
    u16* dst = Bsh[tap];
    #pragma unroll
    for (int i = 0; i < 3; ++i) gload16(sb + bgof[i], dst + bldo[i]);
  };

  // ---- A staging state ----
  const float* arow_ptr = nullptr;           // LAYER1
  const u16* a2src[2] = {nullptr, nullptr};  // LAYER2
  int a2ldo[2] = {0, 0};
  float4 ar0, ar1, ar2, ar3;
  if constexpr (LAYER == 1) {
    // thread t owns slots {t, t+512}: (g1, r1) and (g1+2, r1), r1 = t&255
    int r1 = tid & 255, g1 = tid >> 8;
    int grow = l0 - 1 + r1;
    if (grow > l0 + 135) grow = l0 + 135;    // rows >135 never read: dedupe
    if (grow < 0) grow = 0;
    if (grow > Lz - 1) grow = Lz - 1;
    arow_ptr = (const float*)Asrc + (size_t)b * Lz * 384 + (size_t)grow * 384 +
               g1 * 8;
  } else {
    #pragma unroll
    for (int i = 0; i < 2; ++i) {
      int c = wave + 8 * i;                  // 16 chunks of 1KB
      int s = c * 64 + lane, g = s >> 8, r = s & 255;
      int p = l0 + r;                        // padded row index
      if (p > l0 + 135) p = l0 + 135;
      if (p > Lz + 1) p = Lz + 1;
      a2src[i] = (const u16*)Asrc + (size_t)b * (Lz + 2) * 384 +
                 (size_t)p * 384 + g * 8;
      a2ldo[i] = c * 512;
    }
  }
  auto AISSUE = [&](int w) {                 // LAYER1: load window-w regs
    const float* p = arow_ptr + w * 32;
    ar0 = *reinterpret_cast<const float4*>(p);
    ar1 = *reinterpret_cast<const float4*>(p + 4);
    ar2 = *reinterpret_cast<const float4*>(p + 16);
    ar3 = *reinterpret_cast<const float4*>(p + 20);
  };
  auto ADSW = [&](int wbuf) {                // LAYER1: regs -> LDS bf16
    u16x8 h0, h1;
    h0[0] = f2bf(ar0.x); h0[1] = f2bf(ar0.y); h0[2] = f2bf(ar0.z); h0[3] = f2bf(ar0.w);
    h0[4] = f2bf(ar1.x); h0[5] = f2bf(ar1.y); h0[6] = f2bf(ar1.z); h0[7] = f2bf(ar1.w);
    h1[0] = f2bf(ar2.x); h1[1] = f2bf(ar2.y); h1[2] = f2bf(ar2.z); h1[3] = f2bf(ar2.w);
    h1[4] = f2bf(ar3.x); h1[5] = f2bf(ar3.y); h1[6] = f2bf(ar3.z); h1[7] = f2bf(ar3.w);
    *reinterpret_cast<u16x8*>(&Ash[wbuf][tid * 8]) = h0;
    *reinterpret_cast<u16x8*>(&Ash[wbuf][(tid + 512) * 8]) = h1;
  };
  auto STAGE_A2 = [&](int w, int buf) {      // LAYER2: async A window stage
    #pragma unroll
    for (int i = 0; i < 2; ++i) gload16(a2src[i] + w * 32, &Ash[buf][a2ldo[i]]);
  };

  // ---- fragment offsets ----
  int tr[4], boff[6];
  #pragma unroll
  for (int m = 0; m < 4; ++m) tr[m] = wr * 64 + m * 16 + l15;
  #pragma unroll
  for (int n = 0; n < 6; ++n) {
    int c = wc * 96 + n * 16 + l15;
    boff[n] = c * 32 + (lh ^ ((c >> 1) & 3)) * 8;
  }

  f32x4 acc[4][6] = {};

  // ---- prologue ----
  if constexpr (LAYER == 1) {
    AISSUE(0);
    WAITV(0);
    ADSW(0);
    AISSUE(1);
    __builtin_amdgcn_sched_barrier(0);  // pin: aregs(1) issued before B(0),B(1)
    STAGE_B(0);
    STAGE_B(1);
  } else {
    STAGE_A2(0, 0);
    STAGE_B(0);
    STAGE_A2(1, 1);
    STAGE_B(1);
  }

#define PHASE(T)                                                               \
  {                                                                            \
    if constexpr ((T) == 0) {                                                  \
      if constexpr (LAYER == 2) {                                              \
        if (w == 0) { WAITV(5); } else { WAITV(3); }                           \
      } else { WAITV(3); }                                                     \
    } else if constexpr ((T) == 1) {                                           \
      if (w <= 9) {                                                            \
        if constexpr (LAYER == 1) { WAITV(7); } else { WAITV(5); }             \
      } else { WAITV(3); }                                                     \
    } else {                                                                   \
      if (w <= 9) {                                                            \
        if constexpr (LAYER == 1) { WAITV(7); } else { WAITV(5); }             \
      } else if (w == 10) { WAITV(3); } else { WAITV(0); }                     \
    }                                                                          \
    asm volatile("s_waitcnt lgkmcnt(0)" ::: "memory");                         \
    __builtin_amdgcn_s_barrier();                                              \
    __builtin_amdgcn_sched_barrier(0);                                         \
    const int abuf_ = (LAYER == 1) ? (w & 1) : (w % 3);                        \
    bf16x8 av[4], bv[6];                                                       \
    _Pragma("unroll")                                                          \
    for (int m = 0; m < 4; ++m) {                                              \
      av[m] = *reinterpret_cast<const bf16x8*>(                                \
          &Ash[abuf_][(lh * 256 + tr[m] + (T)) * 8]);                          \
      if constexpr (LAYER == 1 && (T) != 1) {                                  \
        int gr = l0 + tr[m] + (T) - 1;                                         \
        if ((unsigned)gr > (unsigned)(Lz - 1)) av[m] = zfrag;                  \
      }                                                                        \
    }                                                                          \
    _Pragma("unroll")                                                          \
    for (int n = 0; n < 6; ++n)                                                \
      bv[n] = *reinterpret_cast<const bf16x8*>(&Bsh[(T)][boff[n]]);            \
    __builtin_amdgcn_sched_barrier(0);                                         \
    { int kt2_ = 3 * w + (T) + 2; if (kt2_ <= 35) STAGE_B(kt2_); }             \
    __builtin_amdgcn_sched_barrier(0);                                         \
    if constexpr (LAYER == 1 && (T) == 0) {                                    \
      if (w <= 10) ADSW((w + 1) & 1);  /* after av reads, before AISSUE */     \
    }                                                                          \
    if constexpr ((T) == 0) {                                                  \
      if (w <= 9) {                                                            \
        if constexpr (LAYER == 1) { AISSUE(w + 2); }                           \
        else { STAGE_A2(w + 2, (w + 2) % 3); }                                 \
      }                                                                        \
    }                                                                          \
    __builtin_amdgcn_sched_barrier(0);                                         \
    __builtin_amdgcn_s_setprio(1);                                             \
    _Pragma("unroll")                                                          \
    for (int m = 0; m < 4; ++m)                                                \
      _Pragma("unroll")                                                        \
      for (int n = 0; n < 6; ++n)                                              \
        acc[m][n] = __builtin_amdgcn_mfma_f32_16x16x32_bf16(av[m], bv[n],      \
                                                            acc[m][n], 0, 0, 0);\
    __builtin_amdgcn_s_setprio(0);                                             \
  }

  for (int w = 0; w < 12; ++w) {
    PHASE(0)
    PHASE(1)
    PHASE(2)
  }
#undef PHASE

  // ---- epilogue: bias + LayerNorm(F) + ReLU, then store bf16 or dot(lw) ----
  __syncthreads();
  float gv[6], bvv[6], cbv[6], lwv[6];
  #pragma unroll
  for (int n = 0; n < 6; ++n) {
    int c = wc * 96 + n * 16 + l15;
    gv[n] = lng[c]; bvv[n] = lnb[c]; cbv[n] = cbias[c];
    lwv[n] = (LAYER == 2) ? lw[c] : 0.f;
  }
  #pragma unroll
  for (int m = 0; m < 4; ++m) {
    #pragma unroll
    for (int r = 0; r < 4; ++r) {
      float s = 0.f, q2 = 0.f;
      #pragma unroll
      for (int n = 0; n < 6; ++n) {
        float v = acc[m][n][r] + cbv[n];
        s += v; q2 += v * v;
      }
      #pragma unroll
      for (int off = 1; off < 16; off <<= 1) {
        s += __shfl_xor(s, off);
        q2 += __shfl_xor(q2, off);
      }
      if (l15 == 0) {
        int row = wr * 64 + m * 16 + lh * 4 + r;
        s_sum[wc][row] = s;
        s_sq[wc][row] = q2;
      }
    }
  }
  __syncthreads();
  #pragma unroll
  for (int m = 0; m < 4; ++m) {
    #pragma unroll
    for (int r = 0; r < 4; ++r) {
      int row = wr * 64 + m * 16 + lh * 4 + r;
      float S = 0.f, Q = 0.f;
      #pragma unroll
      for (int w = 0; w < 4; ++w) { S += s_sum[w][row]; Q += s_sq[w][row]; }
      float mean = S * (1.f / 384.f);
      float var = Q * (1.f / 384.f) - mean * mean;
      float rstd = rsqrtf(var + EPS);
      float dotp = 0.f;
      #pragma unroll
      for (int n = 0; n < 6; ++n) {
        float v = acc[m][n][r] + cbv[n];
        float y = fmaxf((v - mean) * rstd * gv[n] + bvv[n], 0.f);
        if constexpr (LAYER == 1) {
          int c = wc * 96 + n * 16 + l15;
          hout[((size_t)(b * (Lz + 2) + l0 + row + 1)) * 384 + c] = f2bf(y);
        } else {
          dotp += y * lwv[n];
        }
      }
      if constexpr (LAYER == 2) {
        #pragma unroll
        for (int off = 1; off < 16; off <<= 1) dotp += __shfl_xor(dotp, off);
        if (l15 == 0) s_dot[wc][row] = dotp;
      }
    }
  }
  if constexpr (LAYER == 2) {
    __syncthreads();
    if (tid < 128) {
      float dsum = lbias[0];
      #pragma unroll
      for (int w = 0; w < 4; ++w) dsum += s_dot[w][tid];
      dur[(size_t)b * Lz + l0 + tid] = fmaxf(dsum, 0.f);
    }
  }
}

extern "C" void kernel_launch(void* const* d_in, const int* in_sizes, int n_in,
                              void* d_out, int out_size, void* d_ws, size_t ws_size,
                              hipStream_t stream) {
  (void)in_sizes; (void)n_in; (void)out_size; (void)ws_size;
  const float* x   = (const float*)d_in[0];
  const int* tgt   = (const int*)d_in[1];
  const float* w1  = (const float*)d_in[3];
  const float* c1b = (const float*)d_in[4];
  const float* g1  = (const float*)d_in[5];
  const float* b1  = (const float*)d_in[6];
  const float* w2  = (const float*)d_in[7];
  const float* c2b = (const float*)d_in[8];
  const float* g2  = (const float*)d_in[9];
  const float* b2  = (const float*)d_in[10];
  const float* lw  = (const float*)d_in[11];
  const float* lb  = (const float*)d_in[12];

  float* out0 = (float*)d_out;
  float* dur  = out0 + (size_t)Bz * Mz * Dz;

  const size_t h1_n = (size_t)Bz * (Lz + 2) * Dz;  // 12,607,488 bf16
  const size_t wt_n = (size_t)KWz * Fz * Dz;       // 442,368 bf16
  u16* h1  = (u16*)d_ws;
  u16* w1t = h1 + h1_n;
  u16* w2t = w1t + wt_n;
  int* idxb = (int*)(w2t + wt_n);  // byte offset divisible by 4

  constexpr int PREP_BLKS =
      (2 * KWz * Fz * Dz + Bz * 2 * Dz + 1023) / 1024;  // 888
  k_pre<<<PREP_BLKS + Bz, 1024, 0, stream>>>(w1, w2, w1t, w2t, h1, tgt, idxb);
  k_conv<1><<<256, 512, 0, stream>>>(x, w1t, c1b, g1, b1, h1, nullptr, nullptr,
                                     nullptr);
  k_conv<2><<<256, 512, 0, stream>>>(h1, w2t, c2b, g2, b2, nullptr, lw, lb, dur);
  k_gather<<<4096, 256, 0, stream>>>(x, idxb, out0);
}